// Round 2
// baseline (169.107 us; speedup 1.0000x reference)
//
#include <hip/hip_runtime.h>
#include <hip/hip_bf16.h>

#define D          64
#define N_ROWS     131072
#define TOTAL_ELEM (N_ROWS * D)      // 8388608
#define RPB        512               // rows per block
#define ITERS      (RPB / 16)        // 32
#define NBLK       (N_ROWS / RPB)    // 256

typedef __attribute__((ext_vector_type(4))) float f32x4;
typedef __attribute__((ext_vector_type(8))) short bf16x8;

// pack two fp32 -> two bf16 (truncation) in one v_perm_b32
__device__ __forceinline__ unsigned pkbf(float lo, float hi) {
    return __builtin_amdgcn_perm(__float_as_uint(hi), __float_as_uint(lo), 0x07060302u);
}

// max with DPP-shifted copy (16-lane-row reduce, VALU pipe — no LDS traffic)
// CTRL must be an ICE for the builtin -> template parameter.
template <int CTRL>
__device__ __forceinline__ float dpp_max_step(float x) {
    int y = __builtin_amdgcn_update_dpp(0, __float_as_int(x), CTRL, 0xF, 0xF, false);
    return fmaxf(x, __int_as_float(y));
}

__global__ __launch_bounds__(512)
void vq_kernel(const float* __restrict__ z, const float* __restrict__ cb,
               float* __restrict__ zq, float* __restrict__ lossp) {
    const int tid  = threadIdx.x;
    const int l    = tid & 63;
    const int w    = tid >> 6;      // wave 0..7 owns codes [w*128, w*128+128)
    const int col  = l & 15;
    const int krow = l >> 4;        // 0..3

    __shared__ float wbest[2][8][16];   // [buf][wave][row] packed (score|idx)

    // ---- Phase 0: codebook -> register B-fragments + biases (-||e||^2/2) ----
    bf16x8 bfrag[8][2];
    float  bias[8];
    #pragma unroll
    for (int t = 0; t < 8; ++t) {
        const int code = (w * 8 + t) * 16 + col;
        const float* e = cb + code * D + krow * 8;
        f32x4 e0 = *(const f32x4*)(e);
        f32x4 e1 = *(const f32x4*)(e + 4);
        f32x4 e2 = *(const f32x4*)(e + 32);
        f32x4 e3 = *(const f32x4*)(e + 36);
        float np = 0.f;
        #pragma unroll
        for (int j = 0; j < 4; ++j) {
            np = fmaf(e0[j], e0[j], np); np = fmaf(e1[j], e1[j], np);
            np = fmaf(e2[j], e2[j], np); np = fmaf(e3[j], e3[j], np);
        }
        // sum the 4 lanes (l, l^16, l^32, l^48) holding this code's K-slices
        np += __shfl_xor(np, 16, 64);
        np += __shfl_xor(np, 32, 64);
        bias[t] = -0.5f * np;
        union { bf16x8 v; unsigned u[4]; } b0, b1;
        b0.u[0] = pkbf(e0[0], e0[1]); b0.u[1] = pkbf(e0[2], e0[3]);
        b0.u[2] = pkbf(e1[0], e1[1]); b0.u[3] = pkbf(e1[2], e1[3]);
        b1.u[0] = pkbf(e2[0], e2[1]); b1.u[1] = pkbf(e2[2], e2[3]);
        b1.u[2] = pkbf(e3[0], e3[1]); b1.u[3] = pkbf(e3[2], e3[3]);
        bfrag[t][0] = b0.v; bfrag[t][1] = b1.v;
    }

    const unsigned codebase = (unsigned)(w * 128 + col);
    float lossacc = 0.f;

    for (int it = 0; it < ITERS; ++it) {
        const int rowbase = blockIdx.x * RPB + it * 16;

        // A-fragments straight from global (tile is L2/L1-hot across the 8 waves)
        const float* zr = z + (size_t)(rowbase + col) * D + krow * 8;
        f32x4 z0 = *(const f32x4*)(zr);
        f32x4 z1 = *(const f32x4*)(zr + 4);
        f32x4 z2 = *(const f32x4*)(zr + 32);
        f32x4 z3 = *(const f32x4*)(zr + 36);
        union { bf16x8 v; unsigned u[4]; } a0, a1;
        a0.u[0] = pkbf(z0[0], z0[1]); a0.u[1] = pkbf(z0[2], z0[3]);
        a0.u[2] = pkbf(z1[0], z1[1]); a0.u[3] = pkbf(z1[2], z1[3]);
        a1.u[0] = pkbf(z2[0], z2[1]); a1.u[1] = pkbf(z2[2], z2[3]);
        a1.u[2] = pkbf(z3[0], z3[1]); a1.u[3] = pkbf(z3[2], z3[3]);

        // scores for 16 rows x this wave's 128 codes; running argmax with
        // code index packed into low 10 mantissa bits
        f32x4 run;
        run[0] = run[1] = run[2] = run[3] = -1e30f;
        #pragma unroll
        for (int t = 0; t < 8; ++t) {
            f32x4 acc;
            acc[0] = acc[1] = acc[2] = acc[3] = bias[t];
            acc = __builtin_amdgcn_mfma_f32_16x16x32_bf16(a0.v, bfrag[t][0], acc, 0, 0, 0);
            acc = __builtin_amdgcn_mfma_f32_16x16x32_bf16(a1.v, bfrag[t][1], acc, 0, 0, 0);
            const unsigned idx = codebase + (unsigned)(t * 16);
            #pragma unroll
            for (int j = 0; j < 4; ++j) {
                float pf = __uint_as_float((__float_as_uint(acc[j]) & 0xFFFFFC00u) | idx);
                run[j] = fmaxf(run[j], pf);
            }
        }
        // 16-lane reduce (rows 4g..4g+3 per group handled in parallel)
        #pragma unroll
        for (int j = 0; j < 4; ++j) {
            run[j] = dpp_max_step<0xB1>(run[j]);    // quad_perm xor1
            run[j] = dpp_max_step<0x4E>(run[j]);    // quad_perm xor2
            run[j] = dpp_max_step<0x124>(run[j]);   // row_ror:4
            run[j] = dpp_max_step<0x128>(run[j]);   // row_ror:8
        }
        if (col == 0)
            *(f32x4*)&wbest[it & 1][w][krow * 4] = run;
        __syncthreads();

        // cross-wave reduce (all waves redundantly; lanes 0..15 cover rows 0..15)
        const int rr = col;
        float bb = wbest[it & 1][0][rr];
        #pragma unroll
        for (int wv = 1; wv < 8; ++wv) bb = fmaxf(bb, wbest[it & 1][wv][rr]);
        const int codeAll = (int)(__float_as_uint(bb) & 0x3FFu);
        const int myrow  = 2 * w + (l >> 5);
        const int mycode = __shfl(codeAll, myrow, 64);

        // epilogue: gather fp32 code row, write z_q, accumulate loss
        const int ocol = (l & 31) * 2;
        const float2 ev = *(const float2*)(cb + (size_t)mycode * D + ocol);
        const float2 zv = *(const float2*)(z + (size_t)(rowbase + myrow) * D + ocol);
        lossacc = fmaf(ev.x - zv.x, ev.x - zv.x, lossacc);
        lossacc = fmaf(ev.y - zv.y, ev.y - zv.y, lossacc);
        *(float2*)(zq + (size_t)(rowbase + myrow) * D + ocol) = ev;
    }

    #pragma unroll
    for (int m = 1; m <= 32; m <<= 1)
        lossacc += __shfl_xor(lossacc, m, 64);
    if (l == 0)
        atomicAdd(lossp, lossacc * (1.25f / (float)TOTAL_ELEM));
}

extern "C" void kernel_launch(void* const* d_in, const int* in_sizes, int n_in,
                              void* d_out, int out_size, void* d_ws, size_t ws_size,
                              hipStream_t stream) {
    const float* z  = (const float*)d_in[0];
    const float* cb = (const float*)d_in[1];
    float* zq   = (float*)d_out;
    float* loss = zq + TOTAL_ELEM;   // scalar loss is the last output element
    hipMemsetAsync(loss, 0, sizeof(float), stream);
    vq_kernel<<<NBLK, 512, 0, stream>>>(z, cb, zq, loss);
}

// Round 4
// 156.668 us; speedup vs baseline: 1.0794x; 1.0794x over previous
//
#include <hip/hip_runtime.h>
#include <hip/hip_bf16.h>

#define D          64
#define N_ROWS     131072
#define TOTAL_ELEM (N_ROWS * D)      // 8388608
#define RPB        128               // rows per block
#define ITERS      (RPB / 16)        // 8
#define NBLK       (N_ROWS / RPB)    // 1024

typedef __attribute__((ext_vector_type(4))) float f32x4;
typedef __attribute__((ext_vector_type(8))) short bf16x8;

// pack two fp32 -> two bf16 (truncation) in one v_perm_b32
__device__ __forceinline__ unsigned pkbf(float lo, float hi) {
    return __builtin_amdgcn_perm(__float_as_uint(hi), __float_as_uint(lo), 0x07060302u);
}

// max with DPP-shifted copy (16-lane-row reduce, VALU pipe — no LDS traffic)
template <int CTRL>
__device__ __forceinline__ float dpp_max_step(float x) {
    int y = __builtin_amdgcn_update_dpp(0, __float_as_int(x), CTRL, 0xF, 0xF, false);
    return fmaxf(x, __int_as_float(y));
}

__global__ __launch_bounds__(512)
void vq_kernel(const float* __restrict__ z, const float* __restrict__ cb,
               float* __restrict__ zq, float* __restrict__ lossp) {
    const int tid  = threadIdx.x;
    const int l    = tid & 63;
    const int w    = tid >> 6;      // wave 0..7 owns codes [w*128, w*128+128)
    const int col  = l & 15;
    const int krow = l >> 4;        // 0..3

    __shared__ float wbest[ITERS][8][16];   // [tile][wave][row] packed (score|idx)
    __shared__ float lossred[8];

    // ---- Phase 0: codebook -> register B-fragments + biases (-||e||^2/2) ----
    bf16x8 bfrag[8][2];
    float  bias[8];
    #pragma unroll
    for (int t = 0; t < 8; ++t) {
        const int code = (w * 8 + t) * 16 + col;
        const float* e = cb + code * D + krow * 8;
        f32x4 e0 = *(const f32x4*)(e);
        f32x4 e1 = *(const f32x4*)(e + 4);
        f32x4 e2 = *(const f32x4*)(e + 32);
        f32x4 e3 = *(const f32x4*)(e + 36);
        float np = 0.f;
        #pragma unroll
        for (int j = 0; j < 4; ++j) {
            np = fmaf(e0[j], e0[j], np); np = fmaf(e1[j], e1[j], np);
            np = fmaf(e2[j], e2[j], np); np = fmaf(e3[j], e3[j], np);
        }
        // sum the 4 lanes (l, l^16, l^32, l^48) holding this code's K-slices
        np += __shfl_xor(np, 16, 64);
        np += __shfl_xor(np, 32, 64);
        bias[t] = -0.5f * np;
        union { bf16x8 v; unsigned u[4]; } b0, b1;
        b0.u[0] = pkbf(e0[0], e0[1]); b0.u[1] = pkbf(e0[2], e0[3]);
        b0.u[2] = pkbf(e1[0], e1[1]); b0.u[3] = pkbf(e1[2], e1[3]);
        b1.u[0] = pkbf(e2[0], e2[1]); b1.u[1] = pkbf(e2[2], e2[3]);
        b1.u[2] = pkbf(e3[0], e3[1]); b1.u[3] = pkbf(e3[2], e3[3]);
        bfrag[t][0] = b0.v; bfrag[t][1] = b1.v;
    }

    const unsigned codebase = (unsigned)(w * 128 + col);

    // ---- Phase 1: scoring, NO barriers — each wave writes only its wbest slots
    for (int it = 0; it < ITERS; ++it) {
        const int rowbase = blockIdx.x * RPB + it * 16;

        const float* zr = z + (size_t)(rowbase + col) * D + krow * 8;
        f32x4 z0 = *(const f32x4*)(zr);
        f32x4 z1 = *(const f32x4*)(zr + 4);
        f32x4 z2 = *(const f32x4*)(zr + 32);
        f32x4 z3 = *(const f32x4*)(zr + 36);
        union { bf16x8 v; unsigned u[4]; } a0, a1;
        a0.u[0] = pkbf(z0[0], z0[1]); a0.u[1] = pkbf(z0[2], z0[3]);
        a0.u[2] = pkbf(z1[0], z1[1]); a0.u[3] = pkbf(z1[2], z1[3]);
        a1.u[0] = pkbf(z2[0], z2[1]); a1.u[1] = pkbf(z2[2], z2[3]);
        a1.u[2] = pkbf(z3[0], z3[1]); a1.u[3] = pkbf(z3[2], z3[3]);

        // scores for 16 rows x this wave's 128 codes; running argmax with
        // code index packed into low 10 mantissa bits
        f32x4 run;
        run[0] = run[1] = run[2] = run[3] = -1e30f;
        #pragma unroll
        for (int t = 0; t < 8; ++t) {
            f32x4 acc;
            acc[0] = acc[1] = acc[2] = acc[3] = bias[t];
            acc = __builtin_amdgcn_mfma_f32_16x16x32_bf16(a0.v, bfrag[t][0], acc, 0, 0, 0);
            acc = __builtin_amdgcn_mfma_f32_16x16x32_bf16(a1.v, bfrag[t][1], acc, 0, 0, 0);
            const unsigned idx = codebase + (unsigned)(t * 16);
            #pragma unroll
            for (int j = 0; j < 4; ++j) {
                float pf = __uint_as_float((__float_as_uint(acc[j]) & 0xFFFFFC00u) | idx);
                run[j] = fmaxf(run[j], pf);
            }
        }
        // 16-lane reduce (rows krow*4+j handled in parallel across j)
        #pragma unroll
        for (int j = 0; j < 4; ++j) {
            run[j] = dpp_max_step<0xB1>(run[j]);    // quad_perm xor1
            run[j] = dpp_max_step<0x4E>(run[j]);    // quad_perm xor2
            run[j] = dpp_max_step<0x124>(run[j]);   // row_ror:4
            run[j] = dpp_max_step<0x128>(run[j]);   // row_ror:8
        }
        if (col == 0)
            *(f32x4*)&wbest[it][w][krow * 4] = run;
    }

    __syncthreads();   // the ONLY inter-phase barrier

    // ---- Phase 2: epilogue — wave w owns tile it=w (16 rows), fully parallel
    float lossacc = 0.f;
    {
        const int rowbase2 = blockIdx.x * RPB + w * 16;
        const int rr = l & 15;
        float bb = wbest[w][0][rr];
        #pragma unroll
        for (int wv = 1; wv < 8; ++wv) bb = fmaxf(bb, wbest[w][wv][rr]);
        const int codeAll = (int)(__float_as_uint(bb) & 0x3FFu);
        const int myrow = l >> 2;           // 0..15
        const int sub   = l & 3;            // 16-float chunk within the row
        const int mycode = __shfl(codeAll, myrow, 64);

        const float* ep = cb + (size_t)mycode * D + sub * 16;
        const float* zp = z + (size_t)(rowbase2 + myrow) * D + sub * 16;
        float*       op = zq + (size_t)(rowbase2 + myrow) * D + sub * 16;
        #pragma unroll
        for (int q = 0; q < 4; ++q) {
            f32x4 ev = *(const f32x4*)(ep + q * 4);
            f32x4 zv = *(const f32x4*)(zp + q * 4);
            #pragma unroll
            for (int j = 0; j < 4; ++j) {
                const float dd = ev[j] - zv[j];
                lossacc = fmaf(dd, dd, lossacc);
            }
            *(f32x4*)(op + q * 4) = ev;
        }
    }

    // ---- loss: wave reduce -> LDS -> single atomic per block
    #pragma unroll
    for (int m = 1; m <= 32; m <<= 1)
        lossacc += __shfl_xor(lossacc, m, 64);
    if (l == 0) lossred[w] = lossacc;
    __syncthreads();
    if (tid == 0) {
        float s = 0.f;
        #pragma unroll
        for (int wv = 0; wv < 8; ++wv) s += lossred[wv];
        atomicAdd(lossp, s * (1.25f / (float)TOTAL_ELEM));
    }
}

extern "C" void kernel_launch(void* const* d_in, const int* in_sizes, int n_in,
                              void* d_out, int out_size, void* d_ws, size_t ws_size,
                              hipStream_t stream) {
    const float* z  = (const float*)d_in[0];
    const float* cb = (const float*)d_in[1];
    float* zq   = (float*)d_out;
    float* loss = zq + TOTAL_ELEM;   // scalar loss is the last output element
    hipMemsetAsync(loss, 0, sizeof(float), stream);
    vq_kernel<<<NBLK, 512, 0, stream>>>(z, cb, zq, loss);
}